// Round 19
// baseline (15.329 us; speedup 1.0000x reference)
//
#include <hip/hip_runtime.h>

// Problem constants (from reference)
#define N_ 16
#define A_ 4096
#define G_ 256
#define C_ 80
#define BIG_ 1e8f
#define LN2_ 0.69314718055994531f

// Round 19 = Round 15 champion + float2 (VOP3P-packable) distance math.
// ONLY change vs R15: the local-argmin distance and epilogue pd are written
// as float2 ext-vector subs (compiler emits v_pk_add_f32 with neg mods,
// halving the 4 subs to 2 packed ops; abs-adds stay scalar with abs mods).
// No inline asm (R16 lesson: asm pins scheduling), no structure change.
// Bitwise-identical arithmetic -> absmax must stay 0.0.
// Geometry (proven R15): 2048 blocks x 256 thr = one co-resident generation,
// 8 waves/SIMD at natural VGPR<=64; launch_bounds min-waves MUST stay 4.

#define DPP_XOR1  0xB1   // quad_perm(1,0,3,2)
#define DPP_XOR2  0x4E   // quad_perm(2,3,0,1)
#define DPP_XOR7  0x141  // row_half_mirror
#define DPP_XOR15 0x140  // row_mirror

typedef float v2f __attribute__((ext_vector_type(2)));

template<int CTRL>
__device__ __forceinline__ float dppf(float x) {
    return __int_as_float(__builtin_amdgcn_update_dpp(
        0, __float_as_int(x), CTRL, 0xF, 0xF, true));
}
template<int CTRL>
__device__ __forceinline__ int dppi(int x) {
    return __builtin_amdgcn_update_dpp(0, x, CTRL, 0xF, 0xF, true);
}

template<int CTRL>
__device__ __forceinline__ void argmin_stage(float& d, int& idx) {
    const float od = dppf<CTRL>(d);
    const int   oc = dppi<CTRL>(idx);
    const bool  bt = (od < d) || (od == d && oc < idx);
    d   = bt ? od : d;
    idx = bt ? oc : idx;
}

__global__ __launch_bounds__(256, 4) void cbppl_fused_kernel(
    const float* __restrict__ gt_padded,    // (N, G, 4)
    const float* __restrict__ prop_boxes,   // (N, A, 4)
    const float* __restrict__ pred_boxes,   // (N, A, 4)
    const float* __restrict__ class_logits, // (N, A, C)
    const int*   __restrict__ gt_masks,     // (N, G) bool->int32
    const int*   __restrict__ gt_classes,   // (N, G)
    float* __restrict__ out_cls,            // (N, A)
    float* __restrict__ out_proj)           // (N, A)
{
    __shared__ float4 s_gt[G_];
    __shared__ int    s_cls[G_];

    const int t   = threadIdx.x;
    const int sub = t & 15;                  // lane-in-group
    const int gid = t >> 4;                  // group 0..15 within block
    const int n   = blockIdx.x >> 7;         // 128 blocks per batch
    const int ab  = (blockIdx.x & 127) << 5; // 32 anchors per block

    // ---- one-time: stage masked gt boxes + classes to LDS ----
    {
        const int gidx = n * G_ + t;        // t == g (256 threads)
        float4 g4 = ((const float4*)gt_padded)[gidx];
        if (!gt_masks[gidx]) { g4.x = BIG_; g4.y = BIG_; g4.z = BIG_; g4.w = BIG_; }
        s_gt[t]  = g4;
        s_cls[t] = gt_classes[gidx];
    }
    __syncthreads();

    // ---- one-time: register-cache 16 boxes per lane (interleaved) ----
    float4 b[16];
    #pragma unroll
    for (int m = 0; m < 16; ++m) b[m] = s_gt[sub + (m << 4)];

    // ---- 2 passes: 16 anchors per pass (one per 16-lane group) ----
    for (int p = 0; p < 2; ++p) {
        const int ai  = (p << 4) + gid;
        const int row = n * A_ + ab + ai;

        const float4 pb = ((const float4*)prop_boxes)[row];   // group-broadcast
        const float4 qb = ((const float4*)pred_boxes)[row];
        const v2f plo = {pb.x, pb.y}, phi = {pb.z, pb.w};

        // 5 logit loads issued early (independent of argmin)
        const float* lrow = class_logits + (size_t)row * C_;
        float xv[5];
        #pragma unroll
        for (int k = 0; k < 5; ++k) xv[k] = lrow[sub + (k << 4)];

        // local argmin over this lane's 16 register boxes (packed subs)
        float dloc = INFINITY;
        int   mloc = 0;
        #pragma unroll
        for (int m = 0; m < 16; ++m) {
            const v2f tlo = plo - (v2f){b[m].x, b[m].y};   // v_pk_add_f32 (neg)
            const v2f thi = phi - (v2f){b[m].z, b[m].w};   // v_pk_add_f32 (neg)
            const float d = (fabsf(tlo.x) + fabsf(tlo.y))
                          + (fabsf(thi.x) + fabsf(thi.y)); // abs-mod adds
            if (d < dloc) { dloc = d; mloc = m; }  // lower m = lower g
        }
        int iloc = (mloc << 4) + sub;              // g index

        // 16-lane argmin butterfly on DPP (VALU pipe, no LDS)
        argmin_stage<DPP_XOR1 >(dloc, iloc);
        argmin_stage<DPP_XOR2 >(dloc, iloc);
        argmin_stage<DPP_XOR7 >(dloc, iloc);
        argmin_stage<DPP_XOR15>(dloc, iloc);
        const int   closest  = iloc;
        const int   nonempty = (dloc < BIG_);

        // epilogue lookups: uniform per group -> LDS broadcast
        const float4 cb     = s_gt[closest];
        const int    target = s_cls[closest];
        const v2f qlo = {qb.x, qb.y}, qhi = {qb.z, qb.w};
        const v2f ulo = qlo - (v2f){cb.x, cb.y};
        const v2f uhi = qhi - (v2f){cb.z, cb.w};
        const float pd = (fabsf(ulo.x) + fabsf(ulo.y))
                       + (fabsf(uhi.x) + fabsf(uhi.y));

        // focal, negative-class closed form (branchless; exact identities)
        float acc = 0.0f;
        #pragma unroll
        for (int j = 0; j < 5; ++j) {
            const float x  = xv[j];
            const float u  = __expf(-x);
            const float tt = 1.0f + u;
            const float sp = fmaf(LN2_, __log2f(tt), x);
            const float r  = __builtin_amdgcn_rcpf(tt);
            acc = fmaf(sp, r * r, acc);
        }
        acc *= 0.75f;

        // target-class correction; xt selected from registers (kt uniform)
        {
            const int kt = target >> 4;
            float xt = xv[0];
            xt = (kt == 1) ? xv[1] : xt;
            xt = (kt == 2) ? xv[2] : xt;
            xt = (kt == 3) ? xv[3] : xt;
            xt = (kt == 4) ? xv[4] : xt;
            const float u  = __expf(-xt);
            const float tt = 1.0f + u;
            const float sp = fmaf(LN2_, __log2f(tt), xt);
            const float pp = __builtin_amdgcn_rcpf(tt);
            const float q  = 1.0f - pp;
            const float corr = fmaf(0.25f * (sp - xt), q * q,
                                    -0.75f * sp * pp * pp);
            acc += ((target & 15) == sub) ? corr : 0.0f;  // owner lane adds
        }

        // group sum of focal partials on DPP
        acc += dppf<DPP_XOR1 >(acc);
        acc += dppf<DPP_XOR2 >(acc);
        acc += dppf<DPP_XOR7 >(acc);
        acc += dppf<DPP_XOR15>(acc);

        if (sub == 0) {
            out_cls[row]  = nonempty ? acc * (1.0f / (float)C_) : 0.0f;
            out_proj[row] = nonempty ? pd : 0.0f;
        }
    }
}

extern "C" void kernel_launch(void* const* d_in, const int* in_sizes, int n_in,
                              void* d_out, int out_size, void* d_ws, size_t ws_size,
                              hipStream_t stream) {
    const float* gt_padded    = (const float*)d_in[0];
    const float* prop_boxes   = (const float*)d_in[1];
    const float* pred_boxes   = (const float*)d_in[2];
    const float* class_logits = (const float*)d_in[3];
    const int*   gt_masks     = (const int*)d_in[4];
    const int*   gt_classes   = (const int*)d_in[5];

    float* out = (float*)d_out;
    float* out_cls  = out;             // classification_loss, (N, A)
    float* out_proj = out + N_ * A_;   // projection_loss,     (N, A)

    dim3 grid(N_ * A_ / 32);           // 2048 blocks = one generation
    dim3 block(256);                   // 4 waves; 8 blocks/CU -> 8 waves/SIMD
    cbppl_fused_kernel<<<grid, block, 0, stream>>>(
        gt_padded, prop_boxes, pred_boxes, class_logits,
        gt_masks, gt_classes, out_cls, out_proj);
}

// Round 20
// 13.531 us; speedup vs baseline: 1.1329x; 1.1329x over previous
//
#include <hip/hip_runtime.h>

// Problem constants (from reference)
#define N_ 16
#define A_ 4096
#define G_ 256
#define C_ 80
#define BIG_ 1e8f
#define LN2_ 0.69314718055994531f

// FINAL CHAMPION = Round 15/18 exact (13.64/13.72us, absmax 0.0).
// Structure: 2048 blocks x 256 threads (one co-resident generation:
// 8 blocks/CU x 4 waves = 32 waves/CU = 8 waves/SIMD at the natural
// 64-VGPR allocation; launch_bounds min-waves MUST stay 4 — min-waves=8
// forces VGPR=32 and spills 228MB, R13/R14). 32 anchors/block, 16 groups
// x 2 serial passes; per pass: early loads (pb + qb + 5 logits hoisted;
// HBM latency hides under staging/argmin) -> register-resident 16-box
// local argmin -> 4-stage DPP butterfly argmin (lexicographic (d,idx) =
// exact first-occurrence jnp.argmin) -> branchless focal (closed-form
// negative class + owner-lane target correction from registers) -> DPP sum.
// Masked-out gt boxes staged as (BIG,...): never win; nonempty <=> dmin<BIG.
// Falsified levers (R8 issue-trim, R11 VMEM-compress, R13/14 launch_bounds,
// R16/17 LDS-halving, R16 asm-pk, R19 ext-vector-pk). Clock probe R12:
// effective shader clock ~1.3GHz (DVFS) — kernel is issue+latency-bound
// at that clock; HBM at ~2% of peak (L2-resident inputs).

#define DPP_XOR1  0xB1   // quad_perm(1,0,3,2)
#define DPP_XOR2  0x4E   // quad_perm(2,3,0,1)
#define DPP_XOR7  0x141  // row_half_mirror
#define DPP_XOR15 0x140  // row_mirror

template<int CTRL>
__device__ __forceinline__ float dppf(float x) {
    return __int_as_float(__builtin_amdgcn_update_dpp(
        0, __float_as_int(x), CTRL, 0xF, 0xF, true));
}
template<int CTRL>
__device__ __forceinline__ int dppi(int x) {
    return __builtin_amdgcn_update_dpp(0, x, CTRL, 0xF, 0xF, true);
}

template<int CTRL>
__device__ __forceinline__ void argmin_stage(float& d, int& idx) {
    const float od = dppf<CTRL>(d);
    const int   oc = dppi<CTRL>(idx);
    const bool  bt = (od < d) || (od == d && oc < idx);
    d   = bt ? od : d;
    idx = bt ? oc : idx;
}

__global__ __launch_bounds__(256, 4) void cbppl_fused_kernel(
    const float* __restrict__ gt_padded,    // (N, G, 4)
    const float* __restrict__ prop_boxes,   // (N, A, 4)
    const float* __restrict__ pred_boxes,   // (N, A, 4)
    const float* __restrict__ class_logits, // (N, A, C)
    const int*   __restrict__ gt_masks,     // (N, G) bool->int32
    const int*   __restrict__ gt_classes,   // (N, G)
    float* __restrict__ out_cls,            // (N, A)
    float* __restrict__ out_proj)           // (N, A)
{
    __shared__ float4 s_gt[G_];
    __shared__ int    s_cls[G_];

    const int t   = threadIdx.x;
    const int sub = t & 15;                  // lane-in-group
    const int gid = t >> 4;                  // group 0..15 within block
    const int n   = blockIdx.x >> 7;         // 128 blocks per batch
    const int ab  = (blockIdx.x & 127) << 5; // 32 anchors per block

    // ---- one-time: stage masked gt boxes + classes to LDS ----
    {
        const int gidx = n * G_ + t;        // t == g (256 threads)
        float4 g4 = ((const float4*)gt_padded)[gidx];
        if (!gt_masks[gidx]) { g4.x = BIG_; g4.y = BIG_; g4.z = BIG_; g4.w = BIG_; }
        s_gt[t]  = g4;
        s_cls[t] = gt_classes[gidx];
    }
    __syncthreads();

    // ---- one-time: register-cache 16 boxes per lane (interleaved) ----
    float4 b[16];
    #pragma unroll
    for (int m = 0; m < 16; ++m) b[m] = s_gt[sub + (m << 4)];

    // ---- 2 passes: 16 anchors per pass (one per 16-lane group) ----
    for (int p = 0; p < 2; ++p) {
        const int ai  = (p << 4) + gid;
        const int row = n * A_ + ab + ai;

        const float4 pb = ((const float4*)prop_boxes)[row];   // group-broadcast
        const float4 qb = ((const float4*)pred_boxes)[row];

        // 5 logit loads issued early (independent of argmin)
        const float* lrow = class_logits + (size_t)row * C_;
        float xv[5];
        #pragma unroll
        for (int k = 0; k < 5; ++k) xv[k] = lrow[sub + (k << 4)];

        // local argmin over this lane's 16 register boxes
        float dloc = INFINITY;
        int   mloc = 0;
        #pragma unroll
        for (int m = 0; m < 16; ++m) {
            const float d = fabsf(pb.x - b[m].x) + fabsf(pb.y - b[m].y)
                          + fabsf(pb.z - b[m].z) + fabsf(pb.w - b[m].w);
            if (d < dloc) { dloc = d; mloc = m; }  // lower m = lower g
        }
        int iloc = (mloc << 4) + sub;              // g index

        // 16-lane argmin butterfly on DPP (VALU pipe, no LDS)
        argmin_stage<DPP_XOR1 >(dloc, iloc);
        argmin_stage<DPP_XOR2 >(dloc, iloc);
        argmin_stage<DPP_XOR7 >(dloc, iloc);
        argmin_stage<DPP_XOR15>(dloc, iloc);
        const int   closest  = iloc;
        const int   nonempty = (dloc < BIG_);

        // epilogue lookups: uniform per group -> LDS broadcast
        const float4 cb     = s_gt[closest];
        const int    target = s_cls[closest];
        const float  pd = fabsf(qb.x - cb.x) + fabsf(qb.y - cb.y)
                        + fabsf(qb.z - cb.z) + fabsf(qb.w - cb.w);

        // focal, negative-class closed form (branchless; exact identities)
        float acc = 0.0f;
        #pragma unroll
        for (int j = 0; j < 5; ++j) {
            const float x  = xv[j];
            const float u  = __expf(-x);
            const float tt = 1.0f + u;
            const float sp = fmaf(LN2_, __log2f(tt), x);
            const float r  = __builtin_amdgcn_rcpf(tt);
            acc = fmaf(sp, r * r, acc);
        }
        acc *= 0.75f;

        // target-class correction; xt selected from registers (kt uniform)
        {
            const int kt = target >> 4;
            float xt = xv[0];
            xt = (kt == 1) ? xv[1] : xt;
            xt = (kt == 2) ? xv[2] : xt;
            xt = (kt == 3) ? xv[3] : xt;
            xt = (kt == 4) ? xv[4] : xt;
            const float u  = __expf(-xt);
            const float tt = 1.0f + u;
            const float sp = fmaf(LN2_, __log2f(tt), xt);
            const float pp = __builtin_amdgcn_rcpf(tt);
            const float q  = 1.0f - pp;
            const float corr = fmaf(0.25f * (sp - xt), q * q,
                                    -0.75f * sp * pp * pp);
            acc += ((target & 15) == sub) ? corr : 0.0f;  // owner lane adds
        }

        // group sum of focal partials on DPP
        acc += dppf<DPP_XOR1 >(acc);
        acc += dppf<DPP_XOR2 >(acc);
        acc += dppf<DPP_XOR7 >(acc);
        acc += dppf<DPP_XOR15>(acc);

        if (sub == 0) {
            out_cls[row]  = nonempty ? acc * (1.0f / (float)C_) : 0.0f;
            out_proj[row] = nonempty ? pd : 0.0f;
        }
    }
}

extern "C" void kernel_launch(void* const* d_in, const int* in_sizes, int n_in,
                              void* d_out, int out_size, void* d_ws, size_t ws_size,
                              hipStream_t stream) {
    const float* gt_padded    = (const float*)d_in[0];
    const float* prop_boxes   = (const float*)d_in[1];
    const float* pred_boxes   = (const float*)d_in[2];
    const float* class_logits = (const float*)d_in[3];
    const int*   gt_masks     = (const int*)d_in[4];
    const int*   gt_classes   = (const int*)d_in[5];

    float* out = (float*)d_out;
    float* out_cls  = out;             // classification_loss, (N, A)
    float* out_proj = out + N_ * A_;   // projection_loss,     (N, A)

    dim3 grid(N_ * A_ / 32);           // 2048 blocks = one generation
    dim3 block(256);                   // 4 waves; 8 blocks/CU -> 8 waves/SIMD
    cbppl_fused_kernel<<<grid, block, 0, stream>>>(
        gt_padded, prop_boxes, pred_boxes, class_logits,
        gt_masks, gt_classes, out_cls, out_proj);
}